// Round 8
// baseline (909.484 us; speedup 1.0000x reference)
//
#include <hip/hip_runtime.h>

// SimpleLSTM: 2-layer LSTM (B=512,T=256,F=64,U=128) + Dense(1,relu).
// R16: (4 rows/WG, 128 WGs/layer) + cross-CU A/B overlap.
// R15 proved full-M internals correct but slow: 16-row WGs concentrate 8x
// the activation epilogue on 8x fewer CUs (VALU-chain bound, 3470cyc/step).
// Fix: 4 batch rows per WG at M-rows {0,4,8,12} -> C-layout puts all valid
// rows in reg 0 of every lane -> epilogue = 1 activation set per lane
// (R8's per-step cost) while using only 128 WGs per layer. Layers A and B
// then run CONCURRENTLY on disjoint CU halves (256 WGs total, 1/CU):
// B gated on A's per-8-step published block counter (R13-proven protocol,
// regular launch, one-way dep -> no deadlock, bounded spin -> no hang).
// Total ~272 skewed steps x ~1400cyc instead of 512 x 1390 (R8).
// Rec weights AGPR-pinned + asm MFMA (R11/R15-proven); x-weights streamed
// in calcX (L2-hot, R8-proven). ~100 arch + 64 AGPR per wave, no spill.

#define T_STEPS 256
#define BATCH   512
#define NU      128
#define FDIM    64
#define PH      160      // h row stride in halfs (320B: 2-way bank alias max)
#define XR      129      // xz (s,r)-row stride in f4 (516B: rotates banks)
#define XHALF   (16 * XR)   // f4s per xz buffer

typedef _Float16 h8 __attribute__((ext_vector_type(8)));
typedef float    f4 __attribute__((ext_vector_type(4)));

#define LOG2E    1.4426950408889634f
#define TWOLOG2E 2.8853900817779268f

#define WG_BARRIER() asm volatile("s_waitcnt lgkmcnt(0)\n\ts_barrier" ::: "memory")

// Hot-loop MFMA: B operand from AGPR (builtins force v_accvgpr_read copies,
// R10). END embeds s_nop 7: dependent VALU reads >=8 wait states (R11).
#define MFMA16(d, a, b, c) \
    asm("v_mfma_f32_16x16x32_f16 %0, %1, %2, %3" : "=&v"(d) : "v"(a), "a"(b), "v"(c))
#define MFMA16_ACC(d, a, b) \
    asm("v_mfma_f32_16x16x32_f16 %0, %1, %2, %0" : "+v"(d) : "v"(a), "a"(b))
#define MFMA16_END(d, a, b) \
    asm("v_mfma_f32_16x16x32_f16 %0, %1, %2, %0\n\ts_nop 7" : "+v"(d) : "v"(a), "a"(b))

#if __has_builtin(__builtin_amdgcn_exp2f)
#define EXP2F(x) __builtin_amdgcn_exp2f(x)
#else
#define EXP2F(x) exp2f(x)
#endif
#if __has_builtin(__builtin_amdgcn_rcpf)
#define RCPF(x) __builtin_amdgcn_rcpf(x)
#else
#define RCPF(x) (1.0f / (x))
#endif

__device__ __forceinline__ float sigm2(float s) {   // s = -z*log2e
    return RCPF(1.0f + EXP2F(s));
}
__device__ __forceinline__ float tanh2(float t) {   // t = 2*z*log2e
    return 1.0f - 2.0f * RCPF(1.0f + EXP2F(t));
}

// ---- weight prep: col-major [col][k], fp16, fold gate-specific log2e ----
// gates: 0=i 1=f 2=g 3=o ; i/f/o scaled by -log2e (sigm2), g by +2log2e.
// Also zeroes the 2048-int progress array (64B-strided counters, re-run safe).
__global__ void prep_weights(const float* __restrict__ W1, const float* __restrict__ U1,
                             const float* __restrict__ b1, const float* __restrict__ W2,
                             const float* __restrict__ U2, const float* __restrict__ b2,
                             _Float16* __restrict__ Wp1, _Float16* __restrict__ Up1,
                             _Float16* __restrict__ Wp2, _Float16* __restrict__ Up2,
                             float* __restrict__ bp1, float* __restrict__ bp2,
                             int* __restrict__ prog) {
    int i = blockIdx.x * 256 + threadIdx.x;
    if (i < 32768) {                       // Wp1 [512][64] from W1 [64][512]
        int col = i >> 6, k = i & 63;
        float sc = ((col >> 7) == 2) ? TWOLOG2E : -LOG2E;
        Wp1[i] = (_Float16)(W1[k * 512 + col] * sc);
    } else if (i < 32768 + 65536) {        // Up1 [512][128] from U1 [128][512]
        int j = i - 32768; int col = j >> 7, k = j & 127;
        float sc = ((col >> 7) == 2) ? TWOLOG2E : -LOG2E;
        Up1[j] = (_Float16)(U1[k * 512 + col] * sc);
    } else if (i < 32768 + 131072) {       // Wp2 [512][128] from W2 [128][512]
        int j = i - 98304; int col = j >> 7, k = j & 127;
        float sc = ((col >> 7) == 2) ? TWOLOG2E : -LOG2E;
        Wp2[j] = (_Float16)(W2[k * 512 + col] * sc);
    } else if (i < 32768 + 196608) {       // Up2 [512][128] from U2 [128][512]
        int j = i - 163840; int col = j >> 7, k = j & 127;
        float sc = ((col >> 7) == 2) ? TWOLOG2E : -LOG2E;
        Up2[j] = (_Float16)(U2[k * 512 + col] * sc);
    } else if (i < 32768 + 196608 + 1024) {
        int j = i - 229376;
        if (j < 512) {
            float sc = ((j >> 7) == 2) ? TWOLOG2E : -LOG2E;
            bp1[j] = b1[j] * sc;
        } else {
            int col = j - 512;
            float sc = ((col >> 7) == 2) ? TWOLOG2E : -LOG2E;
            bp2[col] = b2[col] * sc;
        }
    } else if (i < 230400 + 2048) {        // prog[2048] = 0
        prog[i - 230400] = 0;
    }
}

// ---- one LSTM layer, 4 batch rows/WG, M-rows {0,4,8,12} ----
// IS_A: input x f32 [B,T,F]; writes hs fp16 [T,B,U]; publishes prog 1x/8 steps.
// !IS_A: input hs gated on prog (acquire); fused Dense(1,relu) tail.
template <bool IS_A>
__device__ __forceinline__ void layer4(
    const int pair,
    const float* __restrict__ xA, const _Float16* __restrict__ hsIn,
    const _Float16* __restrict__ Wp,   // [512][KX] col-major, scaled fp16
    const _Float16* __restrict__ Up,   // [512][128] col-major, scaled fp16
    const float* __restrict__ bp,      // [512] scaled
    _Float16* __restrict__ hsOut,
    const float* __restrict__ Wd, const float* __restrict__ bd,
    float* __restrict__ dout,
    int* __restrict__ prog,
    f4* smxz, _Float16* smh) {
    constexpr int KX  = IS_A ? 64 : 128;
    constexpr int KXS = KX / 32;

    const int tid  = threadIdx.x;
    const int lane = tid & 63;
    const int wv   = tid >> 6;         // 0..7: wave owns units u0..u0+15, 4 gates
    const int r15  = lane & 15;        // A-row (calcX) / C col
    const int q    = lane >> 4;        // k-quad / C row-group; epilogue row
    const int u0   = wv * 16;
    const int row0 = pair * 4;         // batch rows [row0, row0+4)

    for (int i = tid; i < 2 * 4 * PH; i += 512) smh[i] = (_Float16)0.0f;

    // recurrent weights -> AGPRs (asm MFMA consumes "a" directly)
    h8 uf[4][4];
#pragma unroll
    for (int g = 0; g < 4; g++)
#pragma unroll
        for (int ks = 0; ks < 4; ks++) {
            uf[g][ks] = *(const h8*)&Up[(g * 128 + u0 + r15) * 128 + ks * 32 + q * 8];
            asm("" : "+a"(uf[g][ks]));
        }
    float bias[4];
#pragma unroll
    for (int g = 0; g < 4; g++) bias[g] = bp[g * 128 + u0 + r15];

    // x-block staging: M=16 = 4 steps x 4 rows; A-row m = s*4+r.
    f4 rX[4];    // A: raw f32 x for one block (lane m -> step m>>2, row m&3)
    h8 rH[4];    // B: hs frags for one block
    auto loadA = [&](int blk) {
        int tt = blk * 4 + (r15 >> 2); if (tt > 255) tt = 255;
        const int bb = row0 + (r15 & 3);
        if constexpr (IS_A) {
#pragma unroll
            for (int ks = 0; ks < 2; ks++) {
                const float* p = &xA[((size_t)bb * T_STEPS + tt) * FDIM + ks * 32 + q * 8];
                rX[ks * 2]     = *(const f4*)p;
                rX[ks * 2 + 1] = *(const f4*)(p + 4);
            }
        } else {
#pragma unroll
            for (int ks = 0; ks < 4; ks++)
                rH[ks] = *(const h8*)&hsIn[((size_t)tt * BATCH + bb) * NU + ks * 32 + q * 8];
        }
    };
    auto calcX = [&](int blk) {        // regs -> xz buf (blk&1)
        f4* xzw = &smxz[(blk & 1) * XHALF];
        f4 accx[4];
#pragma unroll
        for (int g = 0; g < 4; g++) accx[g] = (f4){bias[g], bias[g], bias[g], bias[g]};
#pragma unroll
        for (int ks = 0; ks < KXS; ks++) {
            h8 a;
            if constexpr (IS_A) {
#pragma unroll
                for (int j = 0; j < 4; j++) {
                    a[j]     = (_Float16)rX[ks * 2][j];
                    a[4 + j] = (_Float16)rX[ks * 2 + 1][j];
                }
            } else {
                a = rH[ks];
            }
            h8 w[4];   // streamed per block (L2-hot); keeps AGPR budget small
#pragma unroll
            for (int g = 0; g < 4; g++)
                w[g] = *(const h8*)&Wp[(g * 128 + u0 + r15) * KX + ks * 32 + q * 8];
#pragma unroll
            for (int g = 0; g < 4; g++)
                accx[g] = __builtin_amdgcn_mfma_f32_16x16x32_f16(a, w[g], accx[g], 0, 0, 0);
        }
        // C row c = kc*4+rr = s*4+r; write gate-vector f4 at [c][u0+r15]
#pragma unroll
        for (int rr = 0; rr < 4; rr++)
            xzw[(q * 4 + rr) * XR + u0 + r15] =
                (f4){accx[0][rr], accx[1][rr], accx[2][rr], accx[3][rr]};
    };
    // B gating: A publishes one super-block (8 steps = 2 blocks) per bump.
    auto waitS = [&](int need) {
        if constexpr (!IS_A) {
            if (need > 32) need = 32;
            int spins = 0;
            while (__hip_atomic_load(prog + pair * 16, __ATOMIC_ACQUIRE,
                                     __HIP_MEMORY_SCOPE_AGENT) < need) {
                asm volatile("s_sleep 8");
                if (++spins > (1 << 17)) break;
            }
        }
    };

    if constexpr (!IS_A) waitS(2);     // hs blocks 0..3 available
    loadA(0); calcX(0);                // block 0 -> xz buf 0
    loadA(1);                          // in regs for block 1
    __syncthreads();                   // xz buf0 + zeroed h visible

    const h8 hzero = {};
    h8 ha[4];
#pragma unroll
    for (int ks = 0; ks < 4; ks++) ha[ks] = hzero;

    f4 fzero = (f4){0.f, 0.f, 0.f, 0.f};
    asm volatile("" : "+v"(fzero));    // pinned zero-C (no per-step remat)

    float cst = 0.0f;                  // c-state: batch row q, unit u0+r15

    for (int k = 0; k < 64; k++) {
        if constexpr (!IS_A) waitS((k >> 1) + 2);   // covers loadA(k+2)
        if (k < 63) {
            calcX(k + 1);              // consumes regs loaded last boundary
            loadA(k + 2 > 63 ? 63 : k + 2);
        }
#pragma unroll
        for (int s = 0; s < 4; s++) {
            // xz gate-vector: row (s*4 + q), col u0+r15
            f4 xzv = smxz[(k & 1) * XHALF + (s * 4 + q) * XR + u0 + r15];

            // h(t-1) A-frag: lanes lane%4==0 supply A-rows {0,4,8,12}
            // = batch rows 0..3 from buf ((s&1)^1). Other lanes stay zero.
            if ((lane & 3) == 0) {
                const _Float16* hb = &smh[((s & 1) ^ 1) * 4 * PH + (r15 >> 2) * PH];
#pragma unroll
                for (int ks = 0; ks < 4; ks++)
                    ha[ks] = *(const h8*)&hb[ks * 32 + q * 8];
            }

            // rec: z_tile[g] = h @ U[g]; valid C rows {0,4,8,12} -> reg 0
            f4 az0, az1, az2, az3;
            MFMA16(az0, ha[0], uf[0][0], fzero);
            MFMA16(az1, ha[0], uf[1][0], fzero);
            MFMA16(az2, ha[0], uf[2][0], fzero);
            MFMA16(az3, ha[0], uf[3][0], fzero);
#pragma unroll
            for (int ks = 1; ks < 3; ks++) {
                MFMA16_ACC(az0, ha[ks], uf[0][ks]);
                MFMA16_ACC(az1, ha[ks], uf[1][ks]);
                MFMA16_ACC(az2, ha[ks], uf[2][ks]);
                MFMA16_ACC(az3, ha[ks], uf[3][ks]);
            }
            MFMA16_END(az0, ha[3], uf[0][3]);
            MFMA16_END(az1, ha[3], uf[1][3]);
            MFMA16_END(az2, ha[3], uf[2][3]);
            MFMA16_END(az3, ha[3], uf[3][3]);

            // epilogue: ONE activation set per lane (row q, unit u0+r15)
            {
                float gi = sigm2(az0[0] + xzv[0]);
                float gf = sigm2(az1[0] + xzv[1]);
                float gg = tanh2(az2[0] + xzv[2]);
                float go = sigm2(az3[0] + xzv[3]);
                cst = gf * cst + gi * gg;
                float hv = go * tanh2(cst * TWOLOG2E);
                _Float16 h16 = (_Float16)hv;
                smh[(s & 1) * 4 * PH + q * PH + u0 + r15] = h16;
                if constexpr (IS_A) {
                    const int t = k * 4 + s;
                    hsOut[((size_t)t * BATCH + row0 + q) * NU + u0 + r15] = h16;
                }
            }

            if (IS_A && (k & 1) == 1 && s == 3) {
                // publish super-block (8 steps): drain hs stores, sync, add
                asm volatile("s_waitcnt vmcnt(0)" ::: "memory");
                __syncthreads();
                if (tid == 0) {
                    __threadfence();
                    __hip_atomic_fetch_add(prog + pair * 16, 1, __ATOMIC_RELEASE,
                                           __HIP_MEMORY_SCOPE_AGENT);
                }
            } else {
                WG_BARRIER();
            }
        }
    }

    if constexpr (!IS_A) {
        // Dense(1,relu): h(255) in buf 1 (t=255 odd). Wave 0: 16 lanes/row.
        if (wv == 0) {
            const int row = lane >> 4, c = lane & 15;
            float sacc = 0.0f;
#pragma unroll
            for (int j = 0; j < 8; j++) {
                int u = c + 16 * j;
                sacc += (float)smh[4 * PH + row * PH + u] * Wd[u];
            }
            sacc += __shfl_xor(sacc, 8);
            sacc += __shfl_xor(sacc, 4);
            sacc += __shfl_xor(sacc, 2);
            sacc += __shfl_xor(sacc, 1);
            if (c == 0) dout[row0 + row] = fmaxf(sacc + bd[0], 0.0f);
        }
    }
}

// 256 WGs, regular launch, 1 WG/CU: bid<128 -> layer A pair bid;
// bid>=128 -> layer B pair bid-128 (same XCD: 128%8==0). One-way dep.
__global__ __launch_bounds__(512)
__attribute__((amdgpu_waves_per_eu(2, 2))) void lstm_dual4(
    const float* __restrict__ x,
    const _Float16* __restrict__ Wp1, const _Float16* __restrict__ Up1,
    const float* __restrict__ bp1,
    const _Float16* __restrict__ Wp2, const _Float16* __restrict__ Up2,
    const float* __restrict__ bp2,
    _Float16* __restrict__ hs,
    const float* __restrict__ Wd, const float* __restrict__ bd,
    float* __restrict__ dout, int* __restrict__ prog) {
    __shared__ __align__(16) f4 smxz[2 * XHALF];          // 66,048 B
    __shared__ __align__(16) _Float16 smh[2 * 4 * PH];    //  2,560 B
    const int bid = blockIdx.x;
    if (bid < 128)
        layer4<true>(bid, x, nullptr, Wp1, Up1, bp1, hs,
                     nullptr, nullptr, nullptr, prog, smxz, smh);
    else
        layer4<false>(bid - 128, nullptr, hs, Wp2, Up2, bp2, nullptr,
                      Wd, bd, dout, prog, smxz, smh);
}

extern "C" void kernel_launch(void* const* d_in, const int* in_sizes, int n_in,
                              void* d_out, int out_size, void* d_ws, size_t ws_size,
                              hipStream_t stream) {
    const float* x  = (const float*)d_in[0];
    const float* W1 = (const float*)d_in[1];
    const float* U1 = (const float*)d_in[2];
    const float* b1 = (const float*)d_in[3];
    const float* W2 = (const float*)d_in[4];
    const float* U2 = (const float*)d_in[5];
    const float* b2 = (const float*)d_in[6];
    const float* Wd = (const float*)d_in[7];
    const float* bd = (const float*)d_in[8];
    float* out = (float*)d_out;

    const size_t HS    = 33554432;             // hs fp16 [256][512][128]
    const size_t oWp1  = HS;
    const size_t oUp1  = oWp1 + 65536;
    const size_t oWp2  = oUp1 + 131072;
    const size_t oUp2  = oWp2 + 131072;
    const size_t oBp1  = oUp2 + 131072;
    const size_t oBp2  = oBp1 + 2048;
    const size_t oProg = oBp2 + 2048;
    const size_t need  = oProg + 8192;         // 34,025,472
    if (ws_size < need) return;

    char* ws = (char*)d_ws;
    _Float16* hs  = (_Float16*)ws;
    _Float16* Wp1 = (_Float16*)(ws + oWp1);
    _Float16* Up1 = (_Float16*)(ws + oUp1);
    _Float16* Wp2 = (_Float16*)(ws + oWp2);
    _Float16* Up2 = (_Float16*)(ws + oUp2);
    float*    bp1 = (float*)(ws + oBp1);
    float*    bp2 = (float*)(ws + oBp2);
    int*      prog = (int*)(ws + oProg);

    prep_weights<<<908, 256, 0, stream>>>(W1, U1, b1, W2, U2, b2,
                                          Wp1, Up1, Wp2, Up2, bp1, bp2, prog);
    lstm_dual4<<<256, 512, 0, stream>>>(x, Wp1, Up1, bp1, Wp2, Up2, bp2,
                                        hs, Wd, bd, out, prog);
}